// Round 1
// baseline (1302.027 us; speedup 1.0000x reference)
//
#include <hip/hip_runtime.h>

#define ND 8192
#define NG 16384
#define NE 524288
#define FDIM 256
#define H1 64
#define H2 32
#define OUTF 64

typedef float f32x4 __attribute__((ext_vector_type(4)));
typedef float f32x16 __attribute__((ext_vector_type(16)));
typedef __bf16 bf16x8 __attribute__((ext_vector_type(8)));

// ---------------- CSR build ----------------

__global__ void count_kernel(const int* __restrict__ dst, int* __restrict__ cnt, int n) {
    int i = blockIdx.x * 256 + threadIdx.x;
    if (i < n) atomicAdd(&cnt[dst[i]], 1);
}

// one block of 1024 threads; n is 8192 or 16384 (divisible by 1024)
__global__ __launch_bounds__(1024) void scan_kernel(const int* __restrict__ cnt,
                                                    int* __restrict__ off,
                                                    int* __restrict__ fill, int n) {
    __shared__ int part[1024];
    int t = threadIdx.x;
    int items = n >> 10;
    int base = t * items;
    int s = 0;
    for (int i = 0; i < items; ++i) s += cnt[base + i];
    part[t] = s;
    __syncthreads();
    for (int d = 1; d < 1024; d <<= 1) {
        int v = (t >= d) ? part[t - d] : 0;
        __syncthreads();
        part[t] += v;
        __syncthreads();
    }
    int run = (t == 0) ? 0 : part[t - 1];
    for (int i = 0; i < items; ++i) {
        int c = cnt[base + i];
        off[base + i] = run;
        fill[base + i] = run;
        run += c;
    }
    if (t == 1023) off[n] = run;
}

__global__ void fill_kernel(const int* __restrict__ src, const int* __restrict__ dst,
                            int* __restrict__ fill, int* __restrict__ bucket, int n) {
    int i = blockIdx.x * 256 + threadIdx.x;
    if (i < n) {
        int pos = atomicAdd(&fill[dst[i]], 1);
        bucket[pos] = src[i];
    }
}

// ---------------- fused dual projection: out[n][2*HALF] = [X@Wa.T | X@Wb.T] ----------------
// K: input dim; HALF: rows of each W; 256 threads; TPR = 2*HALF/16 threads per row.

template <int K, int HALF>
__global__ __launch_bounds__(256) void proj_kernel(const float* __restrict__ X,
                                                   const float* __restrict__ Wa,
                                                   const float* __restrict__ Wb,
                                                   float* __restrict__ out) {
    constexpr int OUTS = 2 * HALF;
    constexpr int TPR = OUTS / 16;
    constexpr int ROWS = 256 / TPR;
    constexpr int KP = K + 4;
    __shared__ float xs[ROWS][KP];
    int tid = threadIdx.x;
    long row0 = (long)blockIdx.x * ROWS;

    constexpr int TOT4 = ROWS * K / 4;
    const f32x4* X4 = reinterpret_cast<const f32x4*>(X + row0 * K);
    for (int i = tid; i < TOT4; i += 256) {
        int r = i / (K / 4);
        int k4 = i % (K / 4);
        f32x4 v = X4[i];
        xs[r][k4 * 4 + 0] = v.x;
        xs[r][k4 * 4 + 1] = v.y;
        xs[r][k4 * 4 + 2] = v.z;
        xs[r][k4 * 4 + 3] = v.w;
    }
    __syncthreads();

    int r = tid / TPR;
    int b = tid % TPR;
    int obase = b * 16;
    const float* Wp = (obase < HALF) ? (Wa + (long)obase * K) : (Wb + (long)(obase - HALF) * K);

    float acc[16];
#pragma unroll
    for (int j = 0; j < 16; ++j) acc[j] = 0.f;

    for (int k = 0; k < K; k += 4) {
        float x0 = xs[r][k], x1 = xs[r][k + 1], x2 = xs[r][k + 2], x3 = xs[r][k + 3];
#pragma unroll
        for (int j = 0; j < 16; ++j) {
            f32x4 w = *reinterpret_cast<const f32x4*>(Wp + (long)j * K + k);
            acc[j] += x0 * w.x + x1 * w.y + x2 * w.z + x3 * w.w;
        }
    }
    float* orow = out + (row0 + r) * OUTS + obase;
#pragma unroll
    for (int j = 0; j < 16; ++j) orow[j] = acc[j];
}

// ---------------- aggregation: one wave per dst node ----------------
// 64-feature version (layer 1): msrc rows are [128] wide, cols 0..63 are the message proj;
// self rows are [128] wide, cols 64..127 are the self proj.

__global__ __launch_bounds__(256) void agg64_kernel(const int* __restrict__ bucket,
                                                    const int* __restrict__ off,
                                                    const float* __restrict__ msrc,
                                                    const float* __restrict__ bias,
                                                    const float* __restrict__ self,
                                                    float* __restrict__ out) {
    int node = blockIdx.x * 4 + (threadIdx.x >> 6);
    int lane = threadIdx.x & 63;
    int s0 = off[node], s1 = off[node + 1];
    float acc = 0.f;
    int e = s0;
    for (; e + 4 <= s1; e += 4) {
        int i0 = bucket[e], i1 = bucket[e + 1], i2 = bucket[e + 2], i3 = bucket[e + 3];
        acc += msrc[(long)i0 * 128 + lane];
        acc += msrc[(long)i1 * 128 + lane];
        acc += msrc[(long)i2 * 128 + lane];
        acc += msrc[(long)i3 * 128 + lane];
    }
    for (; e < s1; ++e) acc += msrc[(long)bucket[e] * 128 + lane];
    float deg = (float)(s1 - s0);
    out[(long)node * 64 + lane] = acc / fmaxf(deg, 1.f) + bias[lane] + self[(long)node * 128 + 64 + lane];
}

// 32-feature version (layer 2): msrc rows [64] wide cols 0..31; self rows [64] wide cols 32..63.
// Half-wave split: lanes 0..31 do even edges, 32..63 odd edges, combine via shfl_xor.

__global__ __launch_bounds__(256) void agg32_kernel(const int* __restrict__ bucket,
                                                    const int* __restrict__ off,
                                                    const float* __restrict__ msrc,
                                                    const float* __restrict__ bias,
                                                    const float* __restrict__ self,
                                                    float* __restrict__ out) {
    int node = blockIdx.x * 4 + (threadIdx.x >> 6);
    int lane = threadIdx.x & 63;
    int f = lane & 31;
    int half = lane >> 5;
    int s0 = off[node], s1 = off[node + 1];
    float acc = 0.f;
    for (int e = s0 + half; e < s1; e += 2) acc += msrc[(long)bucket[e] * 64 + f];
    acc += __shfl_xor(acc, 32, 64);
    if (half == 0) {
        float deg = (float)(s1 - s0);
        out[(long)node * 32 + f] = acc / fmaxf(deg, 1.f) + bias[f] + self[(long)node * 64 + 32 + f];
    }
}

// ---------------- heads + reparametrize, emit bf16 ----------------

__global__ __launch_bounds__(256) void head_kernel(const float* __restrict__ z,
                                                   const float* __restrict__ Wmu,
                                                   const float* __restrict__ bmu,
                                                   const float* __restrict__ Wlv,
                                                   const float* __restrict__ blv,
                                                   const float* __restrict__ eps,
                                                   __bf16* __restrict__ out) {
    __shared__ float zs[4][36];
    int tid = threadIdx.x;
    int n0 = blockIdx.x * 4;
    if (tid < 128) zs[tid >> 5][tid & 31] = z[(long)n0 * 32 + tid];
    __syncthreads();
    int r = tid >> 6;
    int o = tid & 63;
    long n = n0 + r;
    float mu = bmu[o], lv = blv[o];
#pragma unroll
    for (int k = 0; k < 32; ++k) {
        float zv = zs[r][k];
        mu += zv * Wmu[o * 32 + k];
        lv += zv * Wlv[o * 32 + k];
    }
    float val = mu + eps[n * 64 + o] * expf(lv);
    out[n * 64 + o] = (__bf16)val;
}

// ---------------- final decoder GEMM: C[8192,16384] = A[8192,64] @ B[16384,64]^T ----------------
// bf16 MFMA 32x32x16, wg = 4 waves = 128x128 tile, wave = 64x64 (2x2 frags), K=64 = 4 ksteps.

__global__ __launch_bounds__(256) void final_gemm(const __bf16* __restrict__ A,
                                                  const __bf16* __restrict__ B,
                                                  float* __restrict__ C) {
    int wgm = blockIdx.x & 63;   // 8192/128
    int wgn = blockIdx.x >> 6;   // 128
    int wave = threadIdx.x >> 6;
    int lane = threadIdx.x & 63;
    int m0 = wgm * 128 + (wave & 1) * 64;
    int n0 = wgn * 128 + (wave >> 1) * 64;
    int row = lane & 31;
    int kq = (lane >> 5) * 8;  // which 8-elem half of each K=16 step

    bf16x8 a[2][4], b[2][4];
#pragma unroll
    for (int mf = 0; mf < 2; ++mf) {
        const __bf16* ap = A + (long)(m0 + mf * 32 + row) * 64 + kq;
#pragma unroll
        for (int ks = 0; ks < 4; ++ks) a[mf][ks] = *reinterpret_cast<const bf16x8*>(ap + ks * 16);
    }
#pragma unroll
    for (int nf = 0; nf < 2; ++nf) {
        const __bf16* bp = B + (long)(n0 + nf * 32 + row) * 64 + kq;
#pragma unroll
        for (int ks = 0; ks < 4; ++ks) b[nf][ks] = *reinterpret_cast<const bf16x8*>(bp + ks * 16);
    }

    f32x16 acc[2][2] = {};
#pragma unroll
    for (int ks = 0; ks < 4; ++ks)
#pragma unroll
        for (int mf = 0; mf < 2; ++mf)
#pragma unroll
            for (int nf = 0; nf < 2; ++nf)
                acc[mf][nf] = __builtin_amdgcn_mfma_f32_32x32x16_bf16(a[mf][ks], b[nf][ks], acc[mf][nf], 0, 0, 0);

#pragma unroll
    for (int mf = 0; mf < 2; ++mf)
#pragma unroll
        for (int nf = 0; nf < 2; ++nf)
#pragma unroll
            for (int r = 0; r < 16; ++r) {
                int rr = (r & 3) + 8 * (r >> 2) + 4 * (lane >> 5);
                C[(long)(m0 + mf * 32 + rr) * NG + n0 + nf * 32 + (lane & 31)] = acc[mf][nf][r];
            }
}

// ---------------- launcher ----------------

extern "C" void kernel_launch(void* const* d_in, const int* in_sizes, int n_in,
                              void* d_out, int out_size, void* d_ws, size_t ws_size,
                              hipStream_t stream) {
    const float* x_d   = (const float*)d_in[0];
    const float* x_g   = (const float*)d_in[1];
    const float* W1dgl = (const float*)d_in[2];
    const float* b1dgl = (const float*)d_in[3];
    const float* W1dgr = (const float*)d_in[4];
    const float* W1gdl = (const float*)d_in[5];
    const float* b1gdl = (const float*)d_in[6];
    const float* W1gdr = (const float*)d_in[7];
    const float* W2dgl = (const float*)d_in[8];
    const float* b2dgl = (const float*)d_in[9];
    const float* W2dgr = (const float*)d_in[10];
    const float* W2gdl = (const float*)d_in[11];
    const float* b2gdl = (const float*)d_in[12];
    const float* W2gdr = (const float*)d_in[13];
    const float* Wmu_d = (const float*)d_in[14];
    const float* bmu_d = (const float*)d_in[15];
    const float* Wlv_d = (const float*)d_in[16];
    const float* blv_d = (const float*)d_in[17];
    const float* Wmu_g = (const float*)d_in[18];
    const float* bmu_g = (const float*)d_in[19];
    const float* Wlv_g = (const float*)d_in[20];
    const float* blv_g = (const float*)d_in[21];
    const float* eps_d = (const float*)d_in[22];
    const float* eps_g = (const float*)d_in[23];
    const int* e_dg_src = (const int*)d_in[24];
    const int* e_dg_dst = (const int*)d_in[25];
    const int* e_gd_src = (const int*)d_in[26];
    const int* e_gd_dst = (const int*)d_in[27];

    char* p = (char*)d_ws;
    auto carve = [&](size_t bytes) {
        char* r = p;
        p += (bytes + 255) & ~(size_t)255;
        return r;
    };
    int* cnt_dg    = (int*)carve(NG * 4);
    int* off_dg    = (int*)carve((NG + 1) * 4);
    int* fill_dg   = (int*)carve(NG * 4);
    int* bucket_dg = (int*)carve(NE * 4);
    int* cnt_gd    = (int*)carve(ND * 4);
    int* off_gd    = (int*)carve((ND + 1) * 4);
    int* fill_gd   = (int*)carve(ND * 4);
    int* bucket_gd = (int*)carve(NE * 4);
    float* proj_d1 = (float*)carve((size_t)ND * 128 * 4);  // [.,0:64]=x_d@W1dgl.T  [.,64:128]=x_d@W1gdr.T
    float* proj_g1 = (float*)carve((size_t)NG * 128 * 4);  // [.,0:64]=x_g@W1gdl.T  [.,64:128]=x_g@W1dgr.T
    float* h_d     = (float*)carve((size_t)ND * 64 * 4);
    float* h_g     = (float*)carve((size_t)NG * 64 * 4);
    float* proj2_d = (float*)carve((size_t)ND * 64 * 4);   // [.,0:32]=h_d@W2dgl.T  [.,32:64]=h_d@W2gdr.T
    float* proj2_g = (float*)carve((size_t)NG * 64 * 4);   // [.,0:32]=h_g@W2gdl.T  [.,32:64]=h_g@W2dgr.T
    float* z_d     = (float*)carve((size_t)ND * 32 * 4);
    float* z_g     = (float*)carve((size_t)NG * 32 * 4);
    __bf16* zd_bf  = (__bf16*)carve((size_t)ND * 64 * 2);
    __bf16* zg_bf  = (__bf16*)carve((size_t)NG * 64 * 2);

    // --- CSR build (both relations) ---
    hipMemsetAsync(cnt_dg, 0, NG * 4, stream);
    hipMemsetAsync(cnt_gd, 0, ND * 4, stream);
    count_kernel<<<NE / 256, 256, 0, stream>>>(e_dg_dst, cnt_dg, NE);
    count_kernel<<<NE / 256, 256, 0, stream>>>(e_gd_dst, cnt_gd, NE);
    scan_kernel<<<1, 1024, 0, stream>>>(cnt_dg, off_dg, fill_dg, NG);
    scan_kernel<<<1, 1024, 0, stream>>>(cnt_gd, off_gd, fill_gd, ND);
    fill_kernel<<<NE / 256, 256, 0, stream>>>(e_dg_src, e_dg_dst, fill_dg, bucket_dg, NE);
    fill_kernel<<<NE / 256, 256, 0, stream>>>(e_gd_src, e_gd_dst, fill_gd, bucket_gd, NE);

    // --- layer 1 projections (fused pairs reading each x once) ---
    proj_kernel<256, 64><<<ND / 32, 256, 0, stream>>>(x_d, W1dgl, W1gdr, proj_d1);
    proj_kernel<256, 64><<<NG / 32, 256, 0, stream>>>(x_g, W1gdl, W1dgr, proj_g1);

    // --- layer 1 aggregation ---
    agg64_kernel<<<NG / 4, 256, 0, stream>>>(bucket_dg, off_dg, proj_d1, b1dgl, proj_g1, h_g);
    agg64_kernel<<<ND / 4, 256, 0, stream>>>(bucket_gd, off_gd, proj_g1, b1gdl, proj_d1, h_d);

    // --- layer 2 projections ---
    proj_kernel<64, 32><<<ND / 64, 256, 0, stream>>>(h_d, W2dgl, W2gdr, proj2_d);
    proj_kernel<64, 32><<<NG / 64, 256, 0, stream>>>(h_g, W2gdl, W2dgr, proj2_g);

    // --- layer 2 aggregation ---
    agg32_kernel<<<NG / 4, 256, 0, stream>>>(bucket_dg, off_dg, proj2_d, b2dgl, proj2_g, z_g);
    agg32_kernel<<<ND / 4, 256, 0, stream>>>(bucket_gd, off_gd, proj2_g, b2gdl, proj2_d, z_d);

    // --- heads + reparametrize -> bf16 ---
    head_kernel<<<ND / 4, 256, 0, stream>>>(z_d, Wmu_d, bmu_d, Wlv_d, blv_d, eps_d, zd_bf);
    head_kernel<<<NG / 4, 256, 0, stream>>>(z_g, Wmu_g, bmu_g, Wlv_g, blv_g, eps_g, zg_bf);

    // --- decoder: zd @ zg.T ---
    final_gemm<<<(ND / 128) * (NG / 128), 256, 0, stream>>>(zd_bf, zg_bf, (float*)d_out);
}